// Round 8
// baseline (658.567 us; speedup 1.0000x reference)
//
#include <hip/hip_runtime.h>
#include <math.h>

#define NCAP 10
#define IC   6912
#define NJG  576                  // j-groups (12 j each)
#define NSLOT (NJG * 2)           // part slots (1152 = 8 * 144, XCD-swizzlable)
#define JPG  12

typedef __attribute__((ext_vector_type(4))) float f32x4;
typedef __attribute__((ext_vector_type(8))) short bf16x8;

// fp32 -> bf16 RNE
static __device__ inline unsigned short f2bf(float f) {
    unsigned int u = __float_as_uint(f);
    unsigned int r = u + 0x7FFFu + ((u >> 16) & 1u);
    return (unsigned short)(r >> 16);
}

// lane <-> lane^32 exchange of a bf16x8 fragment (4 dwords)
static __device__ inline bf16x8 shfl32(bf16x8 v) {
    union { bf16x8 s; int i[4]; } u;
    u.s = v;
    #pragma unroll
    for (int t = 0; t < 4; ++t) u.i[t] = __shfl_xor(u.i[t], 32);
    return u.s;
}

// Routing sweep. R8: prep_kernel is GONE — iter 0 builds the W/x fragments
// inline (prep's R5-proven transpose body, verbatim) while computing the
// uniform-c pass, and persists them to w_t/x_t for iters 1-2. Iter 0's
// LDS scratch reuses the vv region (iter 0 never loads vv; 4 waves x 1312
// floats = 5248 = exactly the vv tile).
// Structure (R5-proven): 4 waves = bg_l(2) x nh(2); each wave 16 b's, 5
// capsules, all JPG j's. Per j: 5 MFMAs -> u[5] kept in regs, reused for
// logit dot AND accumulation; softmax couples nh halves only through
// sum(exp) via parity-dbuf LDS strip (one barrier/j-iter); nh waves own
// disjoint outputs -> direct store.
// Layouts (R2/R5-proven): A[m=o=lane&15][k=(lane>>4)*8+t], B[k][b=lane&15],
// D col=lane&15(=b) row=(lane>>4)*4+reg(=o); K 16->32 zero-padded via zero
// fragments on lanes>=32 (D valid on ALL lanes). Fused build: pair body
// yields tile(reg) fragment on its 32-lane half; fw[even]=lanes<32 direct,
// fw[odd]=shfl_xor(32); act-gating keeps lanes>=32 zero.
__global__ __launch_bounds__(256, 4) void sweep_kernel(
    const float* __restrict__ x, const float* __restrict__ W,
    unsigned short* __restrict__ x_t, unsigned short* __restrict__ w_t,
    const float* __restrict__ vsum, float* __restrict__ part,
    int iter, int use_xt)
{
    __shared__ float smem[32 * 164 + 128];   // vv tile (or iter0 scratch) + exchange strip

    const int tid  = threadIdx.x;
    const int lane = tid & 63;
    const int wave = tid >> 6;
    const int bl   = lane & 15;
    const int kq   = lane >> 4;          // 0..3: o-group of D rows
    const bool act = (lane < 32);
    // XCD swizzle: bh-pairs (2k,2k+1) map to blockIdx b,b+8 (same chunk,
    // 144 even -> same XCD, near-simultaneous).
    const int logical = ((int)blockIdx.x & 7) * (NSLOT / 8) + ((int)blockIdx.x >> 3);
    const int bh   = logical & 1;
    const int jg   = logical >> 1;
    const int bg_l = wave & 1;
    const int nh   = wave >> 1;          // capsule half: n = nh*5 + p
    const int b    = bh * 32 + bg_l * 16 + bl;
    const int j0   = jg * JPG;
    const int vrow = (bg_l * 16 + bl) * 164;
    float* exbuf = smem + 5248;          // [parity 2][nh 2][32]

    const f32x4 zf = (f32x4){0.f, 0.f, 0.f, 0.f};
    const bf16x8 zb = (bf16x8){0, 0, 0, 0, 0, 0, 0, 0};

    f32x4 sac[5];
    #pragma unroll
    for (int p = 0; p < 5; ++p) sac[p] = zf;

    if (iter == 0) {
        // ================= fused prep + uniform-c pass =================
        const int lr  = lane & 31;
        const int reg = lane >> 5;
        const int ia  = lr >> 2, oq = lr & 3;
        const int o   = lr & 15, kq2 = lr >> 4;
        float* L0 = smem + wave * 1312;
        const float4* W4 = (const float4*)W;
        const int nbase = nh * 5;

        #pragma unroll
        for (int jt = 0; jt < JPG; ++jt) {
            const int j = j0 + jt;

            // ---- x fragment from raw x (and persist to x_t) ----
            bf16x8 fx = zb;
            if (act) {
                const float* xp = x + ((size_t)b * IC + j) * 16 + kq * 8;
                float4 x0 = *(const float4*)xp, x1 = *(const float4*)(xp + 4);
                fx[0] = (short)f2bf(x0.x); fx[1] = (short)f2bf(x0.y);
                fx[2] = (short)f2bf(x0.z); fx[3] = (short)f2bf(x0.w);
                fx[4] = (short)f2bf(x1.x); fx[5] = (short)f2bf(x1.y);
                fx[6] = (short)f2bf(x1.z); fx[7] = (short)f2bf(x1.w);
                if (use_xt && nh == 0)
                    *(bf16x8*)&x_t[((size_t)j * 4 + bh * 2 + bg_l) * 256 + lane * 8] = fx;
            }

            // ---- build 5 W fragments (3 pairs; pair 2 duplicated) ----
            bf16x8 fw[5];
            #pragma unroll
            for (int p = 0; p < 5; ++p) fw[p] = zb;
            #pragma unroll
            for (int pr = 0; pr < 3; ++pr) {
                const int nA  = nbase + pr * 2;
                const int nB  = (pr < 2) ? (nA + 1) : nA;  // (4,4): no OOB
                const int myn = reg ? nB : nA;
                const int tl  = j * 10 + myn;
                float* L = L0 + (pr & 1) * 656;
                const float4* src = W4 + ((size_t)myn * IC + j) * 64;
                float4 a = src[lr];
                float4 c = src[lr + 32];
                *(float4*)&L[reg * 328 + ia * 20 + oq * 4] = a;
                *(float4*)&L[reg * 328 + (ia + 8) * 20 + oq * 4] = c;
                bf16x8 fr;
                #pragma unroll
                for (int t = 0; t < 8; ++t)
                    fr[t] = (short)f2bf(L[reg * 328 + (kq2 * 8 + t) * 20 + o]);
                if (bh == 0)
                    *(bf16x8*)&w_t[(size_t)tl * 256 + lr * 8] = fr;  // pr=2: both
                                                                     // halves write
                                                                     // same addr+data
                bf16x8 fo = shfl32(fr);          // lane<32 <- tile nB's data
                if (act) {
                    fw[pr * 2] = fr;
                    if (pr < 2) fw[pr * 2 + 1] = fo;
                }
            }

            // ---- 5 MFMAs, uniform c = 0.1 ----
            #pragma unroll
            for (int p = 0; p < 5; ++p) {
                f32x4 u = __builtin_amdgcn_mfma_f32_16x16x32_bf16(fw[p], fx, zf, 0, 0, 0);
                sac[p][0] = fmaf(0.1f, u[0], sac[p][0]);
                sac[p][1] = fmaf(0.1f, u[1], sac[p][1]);
                sac[p][2] = fmaf(0.1f, u[2], sac[p][2]);
                sac[p][3] = fmaf(0.1f, u[3], sac[p][3]);
            }
        }
    } else {
        // ================= routing iters (R7 body, unchanged) =================
        // vectorized vsum -> LDS (float4, 5 per thread)
        const float4* vs4 = (const float4*)(vsum + bh * 5120);
        for (int i = tid; i < 1280; i += 256) {
            const int row = i / 40, col = (i % 40) * 4;
            *(float4*)&smem[row * 164 + col] = vs4[i];
        }
        __syncthreads();

        bf16x8 fw[5]; bf16x8 fx;
        fx = zb;
        #pragma unroll
        for (int p = 0; p < 5; ++p) fw[p] = zb;
        if (act) {
            if (use_xt) {
                fx = *(const bf16x8*)&x_t[((size_t)j0 * 4 + bh * 2 + bg_l) * 256 + lane * 8];
            } else {
                const float* xp = x + ((size_t)b * IC + j0) * 16 + kq * 8;
                float4 x0 = *(const float4*)xp, x1 = *(const float4*)(xp + 4);
                fx[0] = (short)f2bf(x0.x); fx[1] = (short)f2bf(x0.y);
                fx[2] = (short)f2bf(x0.z); fx[3] = (short)f2bf(x0.w);
                fx[4] = (short)f2bf(x1.x); fx[5] = (short)f2bf(x1.y);
                fx[6] = (short)f2bf(x1.z); fx[7] = (short)f2bf(x1.w);
            }
            #pragma unroll
            for (int p = 0; p < 5; ++p)
                fw[p] = *(const bf16x8*)&w_t[((size_t)j0 * NCAP + nh * 5 + p) * 256 + lane * 8];
        }

        #pragma unroll
        for (int jt = 0; jt < JPG; ++jt) {
            const int j1 = j0 + jt + 1;          // only used when jt < JPG-1

            bf16x8 nx = zb;
            if (jt < JPG - 1 && act) {
                if (use_xt) {
                    nx = *(const bf16x8*)&x_t[((size_t)j1 * 4 + bh * 2 + bg_l) * 256 + lane * 8];
                } else {
                    const float* xp = x + ((size_t)b * IC + j1) * 16 + kq * 8;
                    float4 x0 = *(const float4*)xp, x1 = *(const float4*)(xp + 4);
                    nx[0] = (short)f2bf(x0.x); nx[1] = (short)f2bf(x0.y);
                    nx[2] = (short)f2bf(x0.z); nx[3] = (short)f2bf(x0.w);
                    nx[4] = (short)f2bf(x1.x); nx[5] = (short)f2bf(x1.y);
                    nx[6] = (short)f2bf(x1.z); nx[7] = (short)f2bf(x1.w);
                }
            }

            f32x4 u[5];
            #pragma unroll
            for (int p = 0; p < 5; ++p)
                u[p] = __builtin_amdgcn_mfma_f32_16x16x32_bf16(fw[p], fx, zf, 0, 0, 0);

            if (jt < JPG - 1 && act) {
                #pragma unroll
                for (int p = 0; p < 5; ++p)
                    fw[p] = *(const bf16x8*)&w_t[((size_t)j1 * NCAP + nh * 5 + p) * 256 + lane * 8];
            }

            float cc[5];
            #pragma unroll
            for (int p = 0; p < 5; ++p) {
                f32x4 vvn = *(const f32x4*)&smem[vrow + (nh * 5 + p) * 16 + kq * 4];
                float pr = u[p][0] * vvn[0] + u[p][1] * vvn[1]
                         + u[p][2] * vvn[2] + u[p][3] * vvn[3];
                pr += __shfl_xor(pr, 16);
                pr += __shfl_xor(pr, 32);
                cc[p] = pr;
            }
            float s5 = 0.f;
            #pragma unroll
            for (int p = 0; p < 5; ++p) { cc[p] = __expf(cc[p]); s5 += cc[p]; }
            float* ex = exbuf + (jt & 1) * 64;
            if (kq == 0) ex[nh * 32 + bg_l * 16 + bl] = s5;
            __syncthreads();
            const float so = ex[(1 - nh) * 32 + bg_l * 16 + bl];
            const float inv = 1.0f / (s5 + so);
            #pragma unroll
            for (int p = 0; p < 5; ++p) {
                const float cn = cc[p] * inv;
                sac[p][0] = fmaf(cn, u[p][0], sac[p][0]);
                sac[p][1] = fmaf(cn, u[p][1], sac[p][1]);
                sac[p][2] = fmaf(cn, u[p][2], sac[p][2]);
                sac[p][3] = fmaf(cn, u[p][3], sac[p][3]);
            }

            fx = nx;
        }
    }

    // ---- direct store: nh waves own disjoint capsules, no combine ----
    float* pp = part + (size_t)logical * 5120;
    #pragma unroll
    for (int p = 0; p < 5; ++p)
        *(f32x4*)&pp[(bg_l * 16 + bl) * 160 + (nh * 5 + p) * 16 + kq * 4] = sac[p];
}

// Fused reduce (NSLOT slots -> s) + squash + vsum/out. Grid 160 x 1024:
// 16-way k-split; each rq-group covers 36 of the 576 jg-pair super-slots.
__global__ __launch_bounds__(1024) void reduce_kernel(
    const float* __restrict__ part, float* __restrict__ vsum,
    float* __restrict__ out, int iter)
{
    __shared__ float lds[15 * 64];
    const int tid = threadIdx.x;
    const int gi = tid & 63, rq = tid >> 6;       // rq 0..15
    const int g  = blockIdx.x * 64 + gi;          // 0..10239
    const float* p0 = part + g;                   // slot parity encodes bh
    float acc = 0.f;
    for (int k = rq * 36; k < rq * 36 + 36; ++k)  // 16*36 = 576 jg pairs
        acc += p0[(size_t)k * 10240];
    if (rq > 0) lds[(rq - 1) * 64 + gi] = acc;
    __syncthreads();
    if (rq == 0) {
        #pragma unroll
        for (int r = 0; r < 15; ++r) acc += lds[r * 64 + gi];
        float sq = acc * acc;                     // squash over o = bits 0..3
        sq += __shfl_xor(sq, 1);
        sq += __shfl_xor(sq, 2);
        sq += __shfl_xor(sq, 4);
        sq += __shfl_xor(sq, 8);
        float scale = (sq / (1.f + sq)) / sqrtf(sq + 1e-7f);
        float v = scale * acc;
        if (iter == 2)      out[g] = v;
        else if (iter == 0) vsum[g] = v;
        else                vsum[g] += v;
    }
}

extern "C" void kernel_launch(void* const* d_in, const int* in_sizes, int n_in,
                              void* d_out, int out_size, void* d_ws, size_t ws_size,
                              hipStream_t stream) {
    (void)in_sizes; (void)n_in; (void)out_size;
    const float* x = (const float*)d_in[0];   // [64, 6912, 16]
    const float* W = (const float*)d_in[1];   // [10, 6912, 16, 16]
    float* out = (float*)d_out;               // [64, 10, 16]

    const size_t wt_sh = (size_t)IC * NCAP * 256;   // shorts (35.4 MB)
    const size_t xt_sh = (size_t)IC * 4 * 256;      // shorts (14.2 MB)
    const size_t part_f = (size_t)NSLOT * 5120;     // floats (23.6 MB)
    const size_t need_xt = wt_sh * 2 + xt_sh * 2 + part_f * 4 + 10240 * 4;

    int use_xt = (ws_size >= need_xt) ? 1 : 0;
    unsigned short* w_t = (unsigned short*)d_ws;
    unsigned short* x_t = use_xt ? (w_t + wt_sh) : nullptr;
    float* part = (float*)(use_xt ? (void*)(x_t + xt_sh) : (void*)(w_t + wt_sh));
    float* vsum = part + part_f;

    for (int iter = 0; iter < 3; ++iter) {
        sweep_kernel<<<NSLOT, 256, 0, stream>>>(x, W, x_t, w_t, vsum, part, iter, use_xt);
        reduce_kernel<<<160, 1024, 0, stream>>>(part, vsum, out, iter);
    }
}

// Round 9
// 605.697 us; speedup vs baseline: 1.0873x; 1.0873x over previous
//
#include <hip/hip_runtime.h>
#include <math.h>

#define NCAP 10
#define IC   6912
#define NJG  576                  // j-groups (12 j each)
#define NSLOT (NJG * 2)           // part slots (1152 = 8 * 144, XCD-swizzlable)
#define JPG  12

typedef __attribute__((ext_vector_type(4))) float f32x4;
typedef __attribute__((ext_vector_type(8))) short bf16x8;

// fp32 -> bf16 RNE
static __device__ inline unsigned short f2bf(float f) {
    unsigned int u = __float_as_uint(f);
    unsigned int r = u + 0x7FFFu + ((u >> 16) & 1u);
    return (unsigned short)(r >> 16);
}

// lane <-> lane^32 exchange of a bf16x8 fragment (4 dwords)
static __device__ inline bf16x8 shfl32(bf16x8 v) {
    union { bf16x8 s; int i[4]; } u;
    u.s = v;
    #pragma unroll
    for (int t = 0; t < 4; ++t) u.i[t] = __shfl_xor(u.i[t], 32);
    return u.s;
}

// ===== iter-0 sweep: fused prep + uniform-c pass (SEPARATE kernel) =====
// R8 lesson: fusing this with the routing body in ONE kernel made regalloc
// the join of both branches -> scratch spill in BOTH paths (VGPR 84->64,
// +350MB/dispatch scratch traffic, 204us/sweep). Separate __global__
// functions compile independently; the routing kernel returns to R7 codegen.
// Body = prep's R5-proven transpose (verbatim indices), persisting w_t/x_t,
// plus 5 MFMAs with uniform c=0.1. LDS scratch reuses the vv region (iter0
// never loads vv; 4 waves x 1312 floats = 5248 = the vv tile).
// Fragment build: pair body yields tile(reg) fragment on its 32-lane half;
// fw[even]=lanes<32 direct, fw[odd]=shfl_xor(32); act-gating keeps
// lanes>=32 zero (K 16->32 zero-padding preserved).
__global__ __launch_bounds__(256, 4) void sweep0_kernel(
    const float* __restrict__ x, const float* __restrict__ W,
    unsigned short* __restrict__ x_t, unsigned short* __restrict__ w_t,
    float* __restrict__ part, int use_xt)
{
    __shared__ float smem[32 * 164 + 128];

    const int tid  = threadIdx.x;
    const int lane = tid & 63;
    const int wave = tid >> 6;
    const int bl   = lane & 15;
    const int kq   = lane >> 4;
    const bool act = (lane < 32);
    const int logical = ((int)blockIdx.x & 7) * (NSLOT / 8) + ((int)blockIdx.x >> 3);
    const int bh   = logical & 1;
    const int jg   = logical >> 1;
    const int bg_l = wave & 1;
    const int nh   = wave >> 1;
    const int b    = bh * 32 + bg_l * 16 + bl;
    const int j0   = jg * JPG;

    const f32x4 zf = (f32x4){0.f, 0.f, 0.f, 0.f};
    const bf16x8 zb = (bf16x8){0, 0, 0, 0, 0, 0, 0, 0};

    f32x4 sac[5];
    #pragma unroll
    for (int p = 0; p < 5; ++p) sac[p] = zf;

    const int lr  = lane & 31;
    const int reg = lane >> 5;
    const int ia  = lr >> 2, oq = lr & 3;
    const int o   = lr & 15, kq2 = lr >> 4;
    float* L0 = smem + wave * 1312;
    const float4* W4 = (const float4*)W;
    const int nbase = nh * 5;

    #pragma unroll
    for (int jt = 0; jt < JPG; ++jt) {
        const int j = j0 + jt;

        // ---- x fragment from raw x (and persist to x_t) ----
        bf16x8 fx = zb;
        if (act) {
            const float* xp = x + ((size_t)b * IC + j) * 16 + kq * 8;
            float4 x0 = *(const float4*)xp, x1 = *(const float4*)(xp + 4);
            fx[0] = (short)f2bf(x0.x); fx[1] = (short)f2bf(x0.y);
            fx[2] = (short)f2bf(x0.z); fx[3] = (short)f2bf(x0.w);
            fx[4] = (short)f2bf(x1.x); fx[5] = (short)f2bf(x1.y);
            fx[6] = (short)f2bf(x1.z); fx[7] = (short)f2bf(x1.w);
            if (use_xt && nh == 0)
                *(bf16x8*)&x_t[((size_t)j * 4 + bh * 2 + bg_l) * 256 + lane * 8] = fx;
        }

        // ---- build 5 W fragments (3 pairs; pair 2 duplicated) ----
        bf16x8 fw[5];
        #pragma unroll
        for (int p = 0; p < 5; ++p) fw[p] = zb;
        #pragma unroll
        for (int pr = 0; pr < 3; ++pr) {
            const int nA  = nbase + pr * 2;
            const int nB  = (pr < 2) ? (nA + 1) : nA;  // (4,4): no OOB
            const int myn = reg ? nB : nA;
            const int tl  = j * 10 + myn;
            float* L = L0 + (pr & 1) * 656;
            const float4* src = W4 + ((size_t)myn * IC + j) * 64;
            float4 a = src[lr];
            float4 c = src[lr + 32];
            *(float4*)&L[reg * 328 + ia * 20 + oq * 4] = a;
            *(float4*)&L[reg * 328 + (ia + 8) * 20 + oq * 4] = c;
            bf16x8 fr;
            #pragma unroll
            for (int t = 0; t < 8; ++t)
                fr[t] = (short)f2bf(L[reg * 328 + (kq2 * 8 + t) * 20 + o]);
            if (bh == 0)
                *(bf16x8*)&w_t[(size_t)tl * 256 + lr * 8] = fr;  // pr=2: both
                                                                 // reg halves write
                                                                 // same addr+data
            bf16x8 fo = shfl32(fr);              // lane<32 <- tile nB's data
            if (act) {
                fw[pr * 2] = fr;
                if (pr < 2) fw[pr * 2 + 1] = fo;
            }
        }

        // ---- 5 MFMAs, uniform c = 0.1 ----
        #pragma unroll
        for (int p = 0; p < 5; ++p) {
            f32x4 u = __builtin_amdgcn_mfma_f32_16x16x32_bf16(fw[p], fx, zf, 0, 0, 0);
            sac[p][0] = fmaf(0.1f, u[0], sac[p][0]);
            sac[p][1] = fmaf(0.1f, u[1], sac[p][1]);
            sac[p][2] = fmaf(0.1f, u[2], sac[p][2]);
            sac[p][3] = fmaf(0.1f, u[3], sac[p][3]);
        }
    }

    float* pp = part + (size_t)logical * 5120;
    #pragma unroll
    for (int p = 0; p < 5; ++p)
        *(f32x4*)&pp[(bg_l * 16 + bl) * 160 + (nh * 5 + p) * 16 + kq * 4] = sac[p];
}

// ===== routing sweep, iters 1-2 (R7-proven body, UNCHANGED, own kernel) =====
// 4 waves = bg_l(2) x nh(2); each wave 16 b's, 5 capsules, all JPG j's.
// Per j: 5 MFMAs -> u[5] kept in regs, reused for logit dot AND
// accumulation; fw[5] refilled in place; softmax couples nh halves only
// through sum(exp) via parity-dbuf LDS strip (one barrier/j-iter); nh waves
// own disjoint outputs -> direct store.
// Layouts (R2/R5-proven): A[m=o=lane&15][k=(lane>>4)*8+t], B[k][b=lane&15],
// D col=lane&15(=b) row=(lane>>4)*4+reg(=o); K 16->32 zero-padded via zero
// fragments on lanes>=32 (D valid on ALL lanes).
__global__ __launch_bounds__(256, 4) void sweep_kernel(
    const float* __restrict__ x, const unsigned short* __restrict__ x_t,
    const unsigned short* __restrict__ w_t, const float* __restrict__ vsum,
    float* __restrict__ part, int use_xt)
{
    __shared__ float smem[32 * 164 + 128];   // vv tile + exchange strip

    const int tid  = threadIdx.x;
    const int lane = tid & 63;
    const int wave = tid >> 6;
    const int bl   = lane & 15;
    const int kq   = lane >> 4;          // 0..3: o-group of D rows
    const bool act = (lane < 32);
    const int logical = ((int)blockIdx.x & 7) * (NSLOT / 8) + ((int)blockIdx.x >> 3);
    const int bh   = logical & 1;
    const int jg   = logical >> 1;
    const int bg_l = wave & 1;
    const int nh   = wave >> 1;          // capsule half: n = nh*5 + p
    const int b    = bh * 32 + bg_l * 16 + bl;
    const int j0   = jg * JPG;
    const int vrow = (bg_l * 16 + bl) * 164;
    float* exbuf = smem + 5248;          // [parity 2][nh 2][32]

    const f32x4 zf = (f32x4){0.f, 0.f, 0.f, 0.f};
    const bf16x8 zb = (bf16x8){0, 0, 0, 0, 0, 0, 0, 0};

    // vectorized vsum -> LDS (float4, 5 per thread)
    const float4* vs4 = (const float4*)(vsum + bh * 5120);
    for (int i = tid; i < 1280; i += 256) {
        const int row = i / 40, col = (i % 40) * 4;
        *(float4*)&smem[row * 164 + col] = vs4[i];
    }
    __syncthreads();

    f32x4 sac[5];
    #pragma unroll
    for (int p = 0; p < 5; ++p) sac[p] = zf;

    bf16x8 fw[5]; bf16x8 fx;
    fx = zb;
    #pragma unroll
    for (int p = 0; p < 5; ++p) fw[p] = zb;
    if (act) {
        if (use_xt) {
            fx = *(const bf16x8*)&x_t[((size_t)j0 * 4 + bh * 2 + bg_l) * 256 + lane * 8];
        } else {
            const float* xp = x + ((size_t)b * IC + j0) * 16 + kq * 8;
            float4 x0 = *(const float4*)xp, x1 = *(const float4*)(xp + 4);
            fx[0] = (short)f2bf(x0.x); fx[1] = (short)f2bf(x0.y);
            fx[2] = (short)f2bf(x0.z); fx[3] = (short)f2bf(x0.w);
            fx[4] = (short)f2bf(x1.x); fx[5] = (short)f2bf(x1.y);
            fx[6] = (short)f2bf(x1.z); fx[7] = (short)f2bf(x1.w);
        }
        #pragma unroll
        for (int p = 0; p < 5; ++p)
            fw[p] = *(const bf16x8*)&w_t[((size_t)j0 * NCAP + nh * 5 + p) * 256 + lane * 8];
    }

    #pragma unroll
    for (int jt = 0; jt < JPG; ++jt) {
        const int j1 = j0 + jt + 1;          // only used when jt < JPG-1

        bf16x8 nx = zb;
        if (jt < JPG - 1 && act) {
            if (use_xt) {
                nx = *(const bf16x8*)&x_t[((size_t)j1 * 4 + bh * 2 + bg_l) * 256 + lane * 8];
            } else {
                const float* xp = x + ((size_t)b * IC + j1) * 16 + kq * 8;
                float4 x0 = *(const float4*)xp, x1 = *(const float4*)(xp + 4);
                nx[0] = (short)f2bf(x0.x); nx[1] = (short)f2bf(x0.y);
                nx[2] = (short)f2bf(x0.z); nx[3] = (short)f2bf(x0.w);
                nx[4] = (short)f2bf(x1.x); nx[5] = (short)f2bf(x1.y);
                nx[6] = (short)f2bf(x1.z); nx[7] = (short)f2bf(x1.w);
            }
        }

        f32x4 u[5];
        #pragma unroll
        for (int p = 0; p < 5; ++p)
            u[p] = __builtin_amdgcn_mfma_f32_16x16x32_bf16(fw[p], fx, zf, 0, 0, 0);

        if (jt < JPG - 1 && act) {
            #pragma unroll
            for (int p = 0; p < 5; ++p)
                fw[p] = *(const bf16x8*)&w_t[((size_t)j1 * NCAP + nh * 5 + p) * 256 + lane * 8];
        }

        float cc[5];
        #pragma unroll
        for (int p = 0; p < 5; ++p) {
            f32x4 vvn = *(const f32x4*)&smem[vrow + (nh * 5 + p) * 16 + kq * 4];
            float pr = u[p][0] * vvn[0] + u[p][1] * vvn[1]
                     + u[p][2] * vvn[2] + u[p][3] * vvn[3];
            pr += __shfl_xor(pr, 16);
            pr += __shfl_xor(pr, 32);
            cc[p] = pr;
        }
        float s5 = 0.f;
        #pragma unroll
        for (int p = 0; p < 5; ++p) { cc[p] = __expf(cc[p]); s5 += cc[p]; }
        float* ex = exbuf + (jt & 1) * 64;
        if (kq == 0) ex[nh * 32 + bg_l * 16 + bl] = s5;
        __syncthreads();
        const float so = ex[(1 - nh) * 32 + bg_l * 16 + bl];
        const float inv = 1.0f / (s5 + so);
        #pragma unroll
        for (int p = 0; p < 5; ++p) {
            const float cn = cc[p] * inv;
            sac[p][0] = fmaf(cn, u[p][0], sac[p][0]);
            sac[p][1] = fmaf(cn, u[p][1], sac[p][1]);
            sac[p][2] = fmaf(cn, u[p][2], sac[p][2]);
            sac[p][3] = fmaf(cn, u[p][3], sac[p][3]);
        }

        fx = nx;
    }

    float* pp = part + (size_t)logical * 5120;
    #pragma unroll
    for (int p = 0; p < 5; ++p)
        *(f32x4*)&pp[(bg_l * 16 + bl) * 160 + (nh * 5 + p) * 16 + kq * 4] = sac[p];
}

// Fused reduce (NSLOT slots -> s) + squash + vsum/out. Grid 160 x 1024:
// 16-way k-split; each rq-group covers 36 of the 576 jg-pair super-slots.
__global__ __launch_bounds__(1024) void reduce_kernel(
    const float* __restrict__ part, float* __restrict__ vsum,
    float* __restrict__ out, int iter)
{
    __shared__ float lds[15 * 64];
    const int tid = threadIdx.x;
    const int gi = tid & 63, rq = tid >> 6;       // rq 0..15
    const int g  = blockIdx.x * 64 + gi;          // 0..10239
    const float* p0 = part + g;                   // slot parity encodes bh
    float acc = 0.f;
    for (int k = rq * 36; k < rq * 36 + 36; ++k)  // 16*36 = 576 jg pairs
        acc += p0[(size_t)k * 10240];
    if (rq > 0) lds[(rq - 1) * 64 + gi] = acc;
    __syncthreads();
    if (rq == 0) {
        #pragma unroll
        for (int r = 0; r < 15; ++r) acc += lds[r * 64 + gi];
        float sq = acc * acc;                     // squash over o = bits 0..3
        sq += __shfl_xor(sq, 1);
        sq += __shfl_xor(sq, 2);
        sq += __shfl_xor(sq, 4);
        sq += __shfl_xor(sq, 8);
        float scale = (sq / (1.f + sq)) / sqrtf(sq + 1e-7f);
        float v = scale * acc;
        if (iter == 2)      out[g] = v;
        else if (iter == 0) vsum[g] = v;
        else                vsum[g] += v;
    }
}

extern "C" void kernel_launch(void* const* d_in, const int* in_sizes, int n_in,
                              void* d_out, int out_size, void* d_ws, size_t ws_size,
                              hipStream_t stream) {
    (void)in_sizes; (void)n_in; (void)out_size;
    const float* x = (const float*)d_in[0];   // [64, 6912, 16]
    const float* W = (const float*)d_in[1];   // [10, 6912, 16, 16]
    float* out = (float*)d_out;               // [64, 10, 16]

    const size_t wt_sh = (size_t)IC * NCAP * 256;   // shorts (35.4 MB)
    const size_t xt_sh = (size_t)IC * 4 * 256;      // shorts (14.2 MB)
    const size_t part_f = (size_t)NSLOT * 5120;     // floats (23.6 MB)
    const size_t need_xt = wt_sh * 2 + xt_sh * 2 + part_f * 4 + 10240 * 4;

    int use_xt = (ws_size >= need_xt) ? 1 : 0;
    unsigned short* w_t = (unsigned short*)d_ws;
    unsigned short* x_t = use_xt ? (w_t + wt_sh) : nullptr;
    float* part = (float*)(use_xt ? (void*)(x_t + xt_sh) : (void*)(w_t + wt_sh));
    float* vsum = part + part_f;

    sweep0_kernel<<<NSLOT, 256, 0, stream>>>(x, W, x_t, w_t, part, use_xt);
    reduce_kernel<<<160, 1024, 0, stream>>>(part, vsum, out, 0);
    for (int iter = 1; iter < 3; ++iter) {
        sweep_kernel<<<NSLOT, 256, 0, stream>>>(x, x_t, w_t, vsum, part, use_xt);
        reduce_kernel<<<160, 1024, 0, stream>>>(part, vsum, out, iter);
    }
}

// Round 10
// 217.133 us; speedup vs baseline: 3.0330x; 2.7895x over previous
//
#include <hip/hip_runtime.h>
#include <math.h>

#define NCAP 10
#define IC   6912
#define NJG  576                  // j-groups (12 j each): 1152 blocks fit fully
                                  // resident (5 blocks/CU VGPR cap -> 1280 max)
#define NSLOT (NJG * 2)           // part slots (1152 = 8 * 144, XCD-swizzlable)
#define JPG  12
#define WPAIRS ((IC * NCAP) / 2)  // 34560 W tile-pairs
#define WBLK 2048                 // W-transpose blocks (R7: 1024 -> 2048;
                                  // phase was grid-capped at 50% occupancy)

typedef __attribute__((ext_vector_type(4))) float f32x4;
typedef __attribute__((ext_vector_type(8))) short bf16x8;

// fp32 -> bf16 RNE
static __device__ inline unsigned short f2bf(float f) {
    unsigned int u = __float_as_uint(f);
    unsigned int r = u + 0x7FFFu + ((u >> 16) & 1u);
    return (unsigned short)(r >> 16);
}

// Prep: blocks <WBLK transpose W into MFMA A-fragment order (R5-proven body,
// spread over 2x blocks -> ~4.2 iters/wave, occupancy 50->87% LDS-capped);
// blocks >=WBLK convert x into B-fragment order bf16, 2 j per block (all 64
// lanes active).
__global__ __launch_bounds__(256) void prep_kernel(
    const float* __restrict__ x, const float* __restrict__ W,
    unsigned short* __restrict__ w_t, unsigned short* __restrict__ x_t,
    int use_xt)
{
    __shared__ float lds[4 * 1312];
    const int tid  = threadIdx.x;
    const int lane = tid & 63;
    const int wv   = tid >> 6;

    if (blockIdx.x < WBLK) {
        float* L0 = lds + wv * 1312;
        const int gw = blockIdx.x * 4 + wv;          // 0..8191
        const int lr  = lane & 31;
        const int reg = lane >> 5;
        const int ia  = lr >> 2, oq = lr & 3;
        const int o   = lr & 15, kq2 = lr >> 4;
        const float4* W4 = (const float4*)W;
        int itc = 0;
        for (int p = gw; p < WPAIRS; p += WBLK * 4, ++itc) {
            float* L = L0 + (itc & 1) * 656;
            const int tl = p * 2 + reg;          // tile id = j*10 + n
            const int n = tl % 10, j = tl / 10;
            const float4* src = W4 + ((size_t)n * IC + j) * 64;
            float4 a = src[lr];
            float4 c = src[lr + 32];
            *(float4*)&L[reg * 328 + ia * 20 + oq * 4] = a;
            *(float4*)&L[reg * 328 + (ia + 8) * 20 + oq * 4] = c;
            bf16x8 fr;
            #pragma unroll
            for (int t = 0; t < 8; ++t)
                fr[t] = (short)f2bf(L[reg * 328 + (kq2 * 8 + t) * 20 + o]);
            *(bf16x8*)&w_t[(size_t)tl * 256 + lr * 8] = fr;
        }
    } else if (use_xt) {
        const int j  = (blockIdx.x - WBLK) * 2 + (lane >> 5);  // 2 j per block
        const int bg = wv;                       // b-group of 16
        const int l31 = lane & 31;
        const int bl = lane & 15, kq = (lane >> 4) & 1;
        const float* xp = x + ((size_t)(bg * 16 + bl) * IC + j) * 16 + kq * 8;
        float4 x0 = *(const float4*)xp;
        float4 x1 = *(const float4*)(xp + 4);
        bf16x8 fr;
        fr[0] = (short)f2bf(x0.x); fr[1] = (short)f2bf(x0.y);
        fr[2] = (short)f2bf(x0.z); fr[3] = (short)f2bf(x0.w);
        fr[4] = (short)f2bf(x1.x); fr[5] = (short)f2bf(x1.y);
        fr[6] = (short)f2bf(x1.z); fr[7] = (short)f2bf(x1.w);
        *(bf16x8*)&x_t[((size_t)j * 4 + bg) * 256 + l31 * 8] = fr;
    }
}

// Routing sweep (R5-proven structure): 4 waves = bg_l(2) x nh(2); each wave
// 16 b's, 5 capsules, all JPG j's. Per j: 5 MFMAs -> u[5] kept in regs,
// reused for logit dot AND accumulation; fw[5] refilled in place; softmax
// couples nh halves only through sum(exp), exchanged via parity-dbuf LDS
// strip (one barrier/j-iter); nh waves own disjoint outputs -> direct store.
// JPG=12 (grid 1152): fully resident in one round (5 blocks/CU VGPR cap).
// R4 lesson: TLP is register-capped, not grid-capped.
// R9/R8 lesson (rule #19): this TU is a VERIFIED-GOOD compilation unit
// (sweep VGPR 84, no spill). Restructuring the TU (fusing/splitting the
// prep path) perturbed regalloc into scratch spill (VGPR 64, +300MB
// scratch traffic/dispatch, 3x regression) twice. Do not reorganize.
// Layouts (R2/R5-proven): A[m=o=lane&15][k=(lane>>4)*8+t], B[k][b=lane&15],
// D col=lane&15(=b) row=(lane>>4)*4+reg(=o); K 16->32 zero-padded via zero
// fragments on lanes>=32 (D valid on ALL lanes).
__global__ __launch_bounds__(256, 4) void sweep_kernel(
    const float* __restrict__ x, const unsigned short* __restrict__ x_t,
    const unsigned short* __restrict__ w_t, const float* __restrict__ vsum,
    float* __restrict__ part, int iter, int use_xt)
{
    __shared__ float smem[32 * 164 + 128];   // vv tile + exchange strip

    const int tid  = threadIdx.x;
    const int lane = tid & 63;
    const int wave = tid >> 6;
    const int bl   = lane & 15;
    const int kq   = lane >> 4;          // 0..3: o-group of D rows
    const bool act = (lane < 32);
    // XCD swizzle: logical slot; bh-pairs (2k,2k+1) map to blockIdx b,b+8
    // (same chunk since 144 is even -> same XCD, near-simultaneous).
    const int logical = ((int)blockIdx.x & 7) * (NSLOT / 8) + ((int)blockIdx.x >> 3);
    const int bh   = logical & 1;
    const int jg   = logical >> 1;
    const int bg_l = wave & 1;
    const int nh   = wave >> 1;          // capsule half: n = nh*5 + p
    const int b    = bh * 32 + bg_l * 16 + bl;
    const int j0   = jg * JPG;
    const int vrow = (bg_l * 16 + bl) * 164;
    float* exbuf = smem + 5248;          // [parity 2][nh 2][32]

    const f32x4 zf = (f32x4){0.f, 0.f, 0.f, 0.f};
    const bf16x8 zb = (bf16x8){0, 0, 0, 0, 0, 0, 0, 0};

    if (iter > 0) {
        // vectorized vsum -> LDS (float4, 5 per thread)
        const float4* vs4 = (const float4*)(vsum + bh * 5120);
        for (int i = tid; i < 1280; i += 256) {
            const int row = i / 40, col = (i % 40) * 4;
            *(float4*)&smem[row * 164 + col] = vs4[i];
        }
    }
    __syncthreads();

    f32x4 sac[5];
    #pragma unroll
    for (int p = 0; p < 5; ++p) sac[p] = zf;

    // ---- prologue: fragments for j0 ----
    bf16x8 fw[5]; bf16x8 fx;
    fx = zb;
    #pragma unroll
    for (int p = 0; p < 5; ++p) fw[p] = zb;
    if (act) {
        if (use_xt) {
            fx = *(const bf16x8*)&x_t[((size_t)j0 * 4 + bh * 2 + bg_l) * 256 + lane * 8];
        } else {
            const float* xp = x + ((size_t)b * IC + j0) * 16 + kq * 8;
            float4 x0 = *(const float4*)xp, x1 = *(const float4*)(xp + 4);
            fx[0] = (short)f2bf(x0.x); fx[1] = (short)f2bf(x0.y);
            fx[2] = (short)f2bf(x0.z); fx[3] = (short)f2bf(x0.w);
            fx[4] = (short)f2bf(x1.x); fx[5] = (short)f2bf(x1.y);
            fx[6] = (short)f2bf(x1.z); fx[7] = (short)f2bf(x1.w);
        }
        #pragma unroll
        for (int p = 0; p < 5; ++p)
            fw[p] = *(const bf16x8*)&w_t[((size_t)j0 * NCAP + nh * 5 + p) * 256 + lane * 8];
    }

    #pragma unroll
    for (int jt = 0; jt < JPG; ++jt) {
        const int j1 = j0 + jt + 1;          // only used when jt < JPG-1

        // prefetch next x fragment
        bf16x8 nx = zb;
        if (jt < JPG - 1 && act) {
            if (use_xt) {
                nx = *(const bf16x8*)&x_t[((size_t)j1 * 4 + bh * 2 + bg_l) * 256 + lane * 8];
            } else {
                const float* xp = x + ((size_t)b * IC + j1) * 16 + kq * 8;
                float4 x0 = *(const float4*)xp, x1 = *(const float4*)(xp + 4);
                nx[0] = (short)f2bf(x0.x); nx[1] = (short)f2bf(x0.y);
                nx[2] = (short)f2bf(x0.z); nx[3] = (short)f2bf(x0.w);
                nx[4] = (short)f2bf(x1.x); nx[5] = (short)f2bf(x1.y);
                nx[6] = (short)f2bf(x1.z); nx[7] = (short)f2bf(x1.w);
            }
        }

        // ---- single MFMA pass: u kept in registers ----
        f32x4 u[5];
        #pragma unroll
        for (int p = 0; p < 5; ++p)
            u[p] = __builtin_amdgcn_mfma_f32_16x16x32_bf16(fw[p], fx, zf, 0, 0, 0);

        // refill fw in place for next j (in flight during softmax/accum)
        if (jt < JPG - 1 && act) {
            #pragma unroll
            for (int p = 0; p < 5; ++p)
                fw[p] = *(const bf16x8*)&w_t[((size_t)j1 * NCAP + nh * 5 + p) * 256 + lane * 8];
        }

        if (iter == 0) {
            #pragma unroll
            for (int p = 0; p < 5; ++p) {
                sac[p][0] = fmaf(0.1f, u[p][0], sac[p][0]);
                sac[p][1] = fmaf(0.1f, u[p][1], sac[p][1]);
                sac[p][2] = fmaf(0.1f, u[p][2], sac[p][2]);
                sac[p][3] = fmaf(0.1f, u[p][3], sac[p][3]);
            }
        } else {
            // logits for this wave's 5 capsules
            float cc[5];
            #pragma unroll
            for (int p = 0; p < 5; ++p) {
                f32x4 vvn = *(const f32x4*)&smem[vrow + (nh * 5 + p) * 16 + kq * 4];
                float pr = u[p][0] * vvn[0] + u[p][1] * vvn[1]
                         + u[p][2] * vvn[2] + u[p][3] * vvn[3];
                pr += __shfl_xor(pr, 16);
                pr += __shfl_xor(pr, 32);
                cc[p] = pr;
            }
            float s5 = 0.f;
            #pragma unroll
            for (int p = 0; p < 5; ++p) { cc[p] = __expf(cc[p]); s5 += cc[p]; }
            // exchange partial exp-sums between nh halves (parity dbuf,
            // one barrier per j-iter)
            float* ex = exbuf + (jt & 1) * 64;
            if (kq == 0) ex[nh * 32 + bg_l * 16 + bl] = s5;
            __syncthreads();
            const float so = ex[(1 - nh) * 32 + bg_l * 16 + bl];
            const float inv = 1.0f / (s5 + so);
            #pragma unroll
            for (int p = 0; p < 5; ++p) {
                const float cn = cc[p] * inv;
                sac[p][0] = fmaf(cn, u[p][0], sac[p][0]);
                sac[p][1] = fmaf(cn, u[p][1], sac[p][1]);
                sac[p][2] = fmaf(cn, u[p][2], sac[p][2]);
                sac[p][3] = fmaf(cn, u[p][3], sac[p][3]);
            }
        }

        fx = nx;
    }

    // ---- direct store: nh waves own disjoint capsules, no combine ----
    float* pp = part + (size_t)logical * 5120;
    #pragma unroll
    for (int p = 0; p < 5; ++p)
        *(f32x4*)&pp[(bg_l * 16 + bl) * 160 + (nh * 5 + p) * 16 + kq * 4] = sac[p];
}

// Fused reduce (NSLOT slots -> s) + squash + vsum/out. Grid 160 x 1024:
// 16-way k-split; each rq-group covers 36 of the 576 jg-pair super-slots.
__global__ __launch_bounds__(1024) void reduce_kernel(
    const float* __restrict__ part, float* __restrict__ vsum,
    float* __restrict__ out, int iter)
{
    __shared__ float lds[15 * 64];
    const int tid = threadIdx.x;
    const int gi = tid & 63, rq = tid >> 6;       // rq 0..15
    const int g  = blockIdx.x * 64 + gi;          // 0..10239
    const float* p0 = part + g;                   // slot parity encodes bh
    float acc = 0.f;
    for (int k = rq * 36; k < rq * 36 + 36; ++k)  // 16*36 = 576 jg pairs
        acc += p0[(size_t)k * 10240];
    if (rq > 0) lds[(rq - 1) * 64 + gi] = acc;
    __syncthreads();
    if (rq == 0) {
        #pragma unroll
        for (int r = 0; r < 15; ++r) acc += lds[r * 64 + gi];
        float sq = acc * acc;                     // squash over o = bits 0..3
        sq += __shfl_xor(sq, 1);
        sq += __shfl_xor(sq, 2);
        sq += __shfl_xor(sq, 4);
        sq += __shfl_xor(sq, 8);
        float scale = (sq / (1.f + sq)) / sqrtf(sq + 1e-7f);
        float v = scale * acc;
        if (iter == 2)      out[g] = v;
        else if (iter == 0) vsum[g] = v;
        else                vsum[g] += v;
    }
}

extern "C" void kernel_launch(void* const* d_in, const int* in_sizes, int n_in,
                              void* d_out, int out_size, void* d_ws, size_t ws_size,
                              hipStream_t stream) {
    (void)in_sizes; (void)n_in; (void)out_size;
    const float* x = (const float*)d_in[0];   // [64, 6912, 16]
    const float* W = (const float*)d_in[1];   // [10, 6912, 16, 16]
    float* out = (float*)d_out;               // [64, 10, 16]

    const size_t wt_sh = (size_t)IC * NCAP * 256;   // shorts (35.4 MB)
    const size_t xt_sh = (size_t)IC * 4 * 256;      // shorts (14.2 MB)
    const size_t part_f = (size_t)NSLOT * 5120;     // floats (23.6 MB)
    const size_t need_xt = wt_sh * 2 + xt_sh * 2 + part_f * 4 + 10240 * 4;

    int use_xt = (ws_size >= need_xt) ? 1 : 0;
    unsigned short* w_t = (unsigned short*)d_ws;
    unsigned short* x_t = use_xt ? (w_t + wt_sh) : nullptr;
    float* part = (float*)(use_xt ? (void*)(x_t + xt_sh) : (void*)(w_t + wt_sh));
    float* vsum = part + part_f;

    prep_kernel<<<use_xt ? (WBLK + IC / 2) : WBLK, 256, 0, stream>>>(x, W, w_t, x_t, use_xt);
    for (int iter = 0; iter < 3; ++iter) {
        sweep_kernel<<<NSLOT, 256, 0, stream>>>(x, x_t, w_t, vsum, part, iter, use_xt);
        reduce_kernel<<<160, 1024, 0, stream>>>(part, vsum, out, iter);
    }
}

// Round 11
// 216.140 us; speedup vs baseline: 3.0470x; 1.0046x over previous
//
#include <hip/hip_runtime.h>
#include <math.h>

#define NCAP 10
#define IC   6912
#define NJG  576                  // j-groups (12 j each): 1152 blocks fit fully
                                  // resident (5 blocks/CU VGPR cap -> 1280 max)
#define NSLOT (NJG * 2)           // part slots (1152 = 8 * 144, XCD-swizzlable)
#define JPG  12
#define WPAIRS ((IC * NCAP) / 2)  // 34560 W tile-pairs
#define WBLK 2048                 // W-transpose blocks (R7: 1024 -> 2048;
                                  // phase was grid-capped at 50% occupancy)

typedef __attribute__((ext_vector_type(4))) float f32x4;
typedef __attribute__((ext_vector_type(8))) short bf16x8;

// fp32 -> bf16 RNE
static __device__ inline unsigned short f2bf(float f) {
    unsigned int u = __float_as_uint(f);
    unsigned int r = u + 0x7FFFu + ((u >> 16) & 1u);
    return (unsigned short)(r >> 16);
}

// Prep: blocks <WBLK transpose W into MFMA A-fragment order (R5-proven body,
// spread over 2x blocks -> ~4.2 iters/wave, occupancy 50->87% LDS-capped);
// blocks >=WBLK convert x into B-fragment order bf16, 2 j per block (all 64
// lanes active). UNCHANGED from R10 (verified-good TU; rule #19).
__global__ __launch_bounds__(256) void prep_kernel(
    const float* __restrict__ x, const float* __restrict__ W,
    unsigned short* __restrict__ w_t, unsigned short* __restrict__ x_t,
    int use_xt)
{
    __shared__ float lds[4 * 1312];
    const int tid  = threadIdx.x;
    const int lane = tid & 63;
    const int wv   = tid >> 6;

    if (blockIdx.x < WBLK) {
        float* L0 = lds + wv * 1312;
        const int gw = blockIdx.x * 4 + wv;          // 0..8191
        const int lr  = lane & 31;
        const int reg = lane >> 5;
        const int ia  = lr >> 2, oq = lr & 3;
        const int o   = lr & 15, kq2 = lr >> 4;
        const float4* W4 = (const float4*)W;
        int itc = 0;
        for (int p = gw; p < WPAIRS; p += WBLK * 4, ++itc) {
            float* L = L0 + (itc & 1) * 656;
            const int tl = p * 2 + reg;          // tile id = j*10 + n
            const int n = tl % 10, j = tl / 10;
            const float4* src = W4 + ((size_t)n * IC + j) * 64;
            float4 a = src[lr];
            float4 c = src[lr + 32];
            *(float4*)&L[reg * 328 + ia * 20 + oq * 4] = a;
            *(float4*)&L[reg * 328 + (ia + 8) * 20 + oq * 4] = c;
            bf16x8 fr;
            #pragma unroll
            for (int t = 0; t < 8; ++t)
                fr[t] = (short)f2bf(L[reg * 328 + (kq2 * 8 + t) * 20 + o]);
            *(bf16x8*)&w_t[(size_t)tl * 256 + lr * 8] = fr;
        }
    } else if (use_xt) {
        const int j  = (blockIdx.x - WBLK) * 2 + (lane >> 5);  // 2 j per block
        const int bg = wv;                       // b-group of 16
        const int l31 = lane & 31;
        const int bl = lane & 15, kq = (lane >> 4) & 1;
        const float* xp = x + ((size_t)(bg * 16 + bl) * IC + j) * 16 + kq * 8;
        float4 x0 = *(const float4*)xp;
        float4 x1 = *(const float4*)(xp + 4);
        bf16x8 fr;
        fr[0] = (short)f2bf(x0.x); fr[1] = (short)f2bf(x0.y);
        fr[2] = (short)f2bf(x0.z); fr[3] = (short)f2bf(x0.w);
        fr[4] = (short)f2bf(x1.x); fr[5] = (short)f2bf(x1.y);
        fr[6] = (short)f2bf(x1.z); fr[7] = (short)f2bf(x1.w);
        *(bf16x8*)&x_t[((size_t)j * 4 + bg) * 256 + l31 * 8] = fr;
    }
}

// Routing sweep (R5-proven structure): 4 waves = bg_l(2) x nh(2); each wave
// 16 b's, 5 capsules, all JPG j's. Per j: 5 MFMAs -> u[5] kept in regs,
// reused for logit dot AND accumulation; softmax couples nh halves only
// through sum(exp), exchanged via parity-dbuf LDS strip (one barrier/j-iter);
// nh waves own disjoint outputs -> direct store.
// R11 change (only one): w-fragment prefetch uses R2's proven nw_ SHADOW
// buffer, issued at the TOP of the iteration — in-place refill created a
// WAR dep (j+1 loads blocked until j's MFMAs read fw), limiting memory-
// level parallelism; shadow prefetch gives each load the whole iter body
// (~300+cy softmax+barrier) to complete. fw[5]+nw_[5]=40 regs, HALF of
// R2's verified fw[10]+nw_[10]=80 at VGPR 84 — low spill risk.
// R9/R8 lesson (rule #19): do NOT reorganize the TU (kernel set/order);
// that perturbed regalloc into 3x spill regressions twice.
// Layouts (R2/R5-proven): A[m=o=lane&15][k=(lane>>4)*8+t], B[k][b=lane&15],
// D col=lane&15(=b) row=(lane>>4)*4+reg(=o); K 16->32 zero-padded via zero
// fragments on lanes>=32 (D valid on ALL lanes).
__global__ __launch_bounds__(256, 4) void sweep_kernel(
    const float* __restrict__ x, const unsigned short* __restrict__ x_t,
    const unsigned short* __restrict__ w_t, const float* __restrict__ vsum,
    float* __restrict__ part, int iter, int use_xt)
{
    __shared__ float smem[32 * 164 + 128];   // vv tile + exchange strip

    const int tid  = threadIdx.x;
    const int lane = tid & 63;
    const int wave = tid >> 6;
    const int bl   = lane & 15;
    const int kq   = lane >> 4;          // 0..3: o-group of D rows
    const bool act = (lane < 32);
    // XCD swizzle: logical slot; bh-pairs (2k,2k+1) map to blockIdx b,b+8
    // (same chunk since 144 is even -> same XCD, near-simultaneous).
    const int logical = ((int)blockIdx.x & 7) * (NSLOT / 8) + ((int)blockIdx.x >> 3);
    const int bh   = logical & 1;
    const int jg   = logical >> 1;
    const int bg_l = wave & 1;
    const int nh   = wave >> 1;          // capsule half: n = nh*5 + p
    const int b    = bh * 32 + bg_l * 16 + bl;
    const int j0   = jg * JPG;
    const int vrow = (bg_l * 16 + bl) * 164;
    float* exbuf = smem + 5248;          // [parity 2][nh 2][32]

    const f32x4 zf = (f32x4){0.f, 0.f, 0.f, 0.f};
    const bf16x8 zb = (bf16x8){0, 0, 0, 0, 0, 0, 0, 0};

    if (iter > 0) {
        // vectorized vsum -> LDS (float4, 5 per thread)
        const float4* vs4 = (const float4*)(vsum + bh * 5120);
        for (int i = tid; i < 1280; i += 256) {
            const int row = i / 40, col = (i % 40) * 4;
            *(float4*)&smem[row * 164 + col] = vs4[i];
        }
    }
    __syncthreads();

    f32x4 sac[5];
    #pragma unroll
    for (int p = 0; p < 5; ++p) sac[p] = zf;

    // ---- prologue: fragments for j0 ----
    bf16x8 fw[5]; bf16x8 fx;
    fx = zb;
    #pragma unroll
    for (int p = 0; p < 5; ++p) fw[p] = zb;
    if (act) {
        if (use_xt) {
            fx = *(const bf16x8*)&x_t[((size_t)j0 * 4 + bh * 2 + bg_l) * 256 + lane * 8];
        } else {
            const float* xp = x + ((size_t)b * IC + j0) * 16 + kq * 8;
            float4 x0 = *(const float4*)xp, x1 = *(const float4*)(xp + 4);
            fx[0] = (short)f2bf(x0.x); fx[1] = (short)f2bf(x0.y);
            fx[2] = (short)f2bf(x0.z); fx[3] = (short)f2bf(x0.w);
            fx[4] = (short)f2bf(x1.x); fx[5] = (short)f2bf(x1.y);
            fx[6] = (short)f2bf(x1.z); fx[7] = (short)f2bf(x1.w);
        }
        #pragma unroll
        for (int p = 0; p < 5; ++p)
            fw[p] = *(const bf16x8*)&w_t[((size_t)j0 * NCAP + nh * 5 + p) * 256 + lane * 8];
    }

    #pragma unroll
    for (int jt = 0; jt < JPG; ++jt) {
        const int j1 = j0 + jt + 1;          // only used when jt < JPG-1

        // ---- prefetch j+1 into shadow buffers (issued BEFORE j's MFMAs:
        //      loads stay in flight across the whole softmax/barrier body) ----
        bf16x8 nw_[5]; bf16x8 nx;
        nx = zb;
        #pragma unroll
        for (int p = 0; p < 5; ++p) nw_[p] = zb;
        if (jt < JPG - 1 && act) {
            if (use_xt) {
                nx = *(const bf16x8*)&x_t[((size_t)j1 * 4 + bh * 2 + bg_l) * 256 + lane * 8];
            } else {
                const float* xp = x + ((size_t)b * IC + j1) * 16 + kq * 8;
                float4 x0 = *(const float4*)xp, x1 = *(const float4*)(xp + 4);
                nx[0] = (short)f2bf(x0.x); nx[1] = (short)f2bf(x0.y);
                nx[2] = (short)f2bf(x0.z); nx[3] = (short)f2bf(x0.w);
                nx[4] = (short)f2bf(x1.x); nx[5] = (short)f2bf(x1.y);
                nx[6] = (short)f2bf(x1.z); nx[7] = (short)f2bf(x1.w);
            }
            #pragma unroll
            for (int p = 0; p < 5; ++p)
                nw_[p] = *(const bf16x8*)&w_t[((size_t)j1 * NCAP + nh * 5 + p) * 256 + lane * 8];
        }

        // ---- single MFMA pass: u kept in registers ----
        f32x4 u[5];
        #pragma unroll
        for (int p = 0; p < 5; ++p)
            u[p] = __builtin_amdgcn_mfma_f32_16x16x32_bf16(fw[p], fx, zf, 0, 0, 0);

        if (iter == 0) {
            #pragma unroll
            for (int p = 0; p < 5; ++p) {
                sac[p][0] = fmaf(0.1f, u[p][0], sac[p][0]);
                sac[p][1] = fmaf(0.1f, u[p][1], sac[p][1]);
                sac[p][2] = fmaf(0.1f, u[p][2], sac[p][2]);
                sac[p][3] = fmaf(0.1f, u[p][3], sac[p][3]);
            }
        } else {
            // logits for this wave's 5 capsules
            float cc[5];
            #pragma unroll
            for (int p = 0; p < 5; ++p) {
                f32x4 vvn = *(const f32x4*)&smem[vrow + (nh * 5 + p) * 16 + kq * 4];
                float pr = u[p][0] * vvn[0] + u[p][1] * vvn[1]
                         + u[p][2] * vvn[2] + u[p][3] * vvn[3];
                pr += __shfl_xor(pr, 16);
                pr += __shfl_xor(pr, 32);
                cc[p] = pr;
            }
            float s5 = 0.f;
            #pragma unroll
            for (int p = 0; p < 5; ++p) { cc[p] = __expf(cc[p]); s5 += cc[p]; }
            // exchange partial exp-sums between nh halves (parity dbuf,
            // one barrier per j-iter)
            float* ex = exbuf + (jt & 1) * 64;
            if (kq == 0) ex[nh * 32 + bg_l * 16 + bl] = s5;
            __syncthreads();
            const float so = ex[(1 - nh) * 32 + bg_l * 16 + bl];
            const float inv = 1.0f / (s5 + so);
            #pragma unroll
            for (int p = 0; p < 5; ++p) {
                const float cn = cc[p] * inv;
                sac[p][0] = fmaf(cn, u[p][0], sac[p][0]);
                sac[p][1] = fmaf(cn, u[p][1], sac[p][1]);
                sac[p][2] = fmaf(cn, u[p][2], sac[p][2]);
                sac[p][3] = fmaf(cn, u[p][3], sac[p][3]);
            }
        }

        // rotate shadow buffers (vanishes under full unroll)
        fx = nx;
        #pragma unroll
        for (int p = 0; p < 5; ++p) fw[p] = nw_[p];
    }

    // ---- direct store: nh waves own disjoint capsules, no combine ----
    float* pp = part + (size_t)logical * 5120;
    #pragma unroll
    for (int p = 0; p < 5; ++p)
        *(f32x4*)&pp[(bg_l * 16 + bl) * 160 + (nh * 5 + p) * 16 + kq * 4] = sac[p];
}

// Fused reduce (NSLOT slots -> s) + squash + vsum/out. Grid 160 x 1024:
// 16-way k-split; each rq-group covers 36 of the 576 jg-pair super-slots.
__global__ __launch_bounds__(1024) void reduce_kernel(
    const float* __restrict__ part, float* __restrict__ vsum,
    float* __restrict__ out, int iter)
{
    __shared__ float lds[15 * 64];
    const int tid = threadIdx.x;
    const int gi = tid & 63, rq = tid >> 6;       // rq 0..15
    const int g  = blockIdx.x * 64 + gi;          // 0..10239
    const float* p0 = part + g;                   // slot parity encodes bh
    float acc = 0.f;
    for (int k = rq * 36; k < rq * 36 + 36; ++k)  // 16*36 = 576 jg pairs
        acc += p0[(size_t)k * 10240];
    if (rq > 0) lds[(rq - 1) * 64 + gi] = acc;
    __syncthreads();
    if (rq == 0) {
        #pragma unroll
        for (int r = 0; r < 15; ++r) acc += lds[r * 64 + gi];
        float sq = acc * acc;                     // squash over o = bits 0..3
        sq += __shfl_xor(sq, 1);
        sq += __shfl_xor(sq, 2);
        sq += __shfl_xor(sq, 4);
        sq += __shfl_xor(sq, 8);
        float scale = (sq / (1.f + sq)) / sqrtf(sq + 1e-7f);
        float v = scale * acc;
        if (iter == 2)      out[g] = v;
        else if (iter == 0) vsum[g] = v;
        else                vsum[g] += v;
    }
}

extern "C" void kernel_launch(void* const* d_in, const int* in_sizes, int n_in,
                              void* d_out, int out_size, void* d_ws, size_t ws_size,
                              hipStream_t stream) {
    (void)in_sizes; (void)n_in; (void)out_size;
    const float* x = (const float*)d_in[0];   // [64, 6912, 16]
    const float* W = (const float*)d_in[1];   // [10, 6912, 16, 16]
    float* out = (float*)d_out;               // [64, 10, 16]

    const size_t wt_sh = (size_t)IC * NCAP * 256;   // shorts (35.4 MB)
    const size_t xt_sh = (size_t)IC * 4 * 256;      // shorts (14.2 MB)
    const size_t part_f = (size_t)NSLOT * 5120;     // floats (23.6 MB)
    const size_t need_xt = wt_sh * 2 + xt_sh * 2 + part_f * 4 + 10240 * 4;

    int use_xt = (ws_size >= need_xt) ? 1 : 0;
    unsigned short* w_t = (unsigned short*)d_ws;
    unsigned short* x_t = use_xt ? (w_t + wt_sh) : nullptr;
    float* part = (float*)(use_xt ? (void*)(x_t + xt_sh) : (void*)(w_t + wt_sh));
    float* vsum = part + part_f;

    prep_kernel<<<use_xt ? (WBLK + IC / 2) : WBLK, 256, 0, stream>>>(x, W, w_t, x_t, use_xt);
    for (int iter = 0; iter < 3; ++iter) {
        sweep_kernel<<<NSLOT, 256, 0, stream>>>(x, x_t, w_t, vsum, part, iter, use_xt);
        reduce_kernel<<<160, 1024, 0, stream>>>(part, vsum, out, iter);
    }
}